// Round 7
// baseline (354.619 us; speedup 1.0000x reference)
//
#include <hip/hip_runtime.h>
#include <hip/hip_fp16.h>

// ---------------------------------------------------------------------------
// DeterministicLSTMSensorBasedForwardDynamics on MI355X (gfx950) — round 7
//
// Round-6 validated the resource model (spill gone, VGPR 124, 263 us). Step
// budget ~11.5K cyc vs ~6.9K stream-port floor -> serialization gap. Main
// culprit: __syncthreads emits s_waitcnt vmcnt(0) before s_barrier (m97/m131
// structural finding), draining the cross-step stream ring every step.
// Round-7:
//   * LDS-only barrier (s_waitcnt lgkmcnt(0); s_barrier) for all intra-kernel
//     barriers: h/x visibility is ds_write-only (lgkm); global stream/x loads
//     legally stay in flight across the barrier -> true cross-step pipeline.
//   * Gate bias folded into MFMA C-init (bias uniform across a lane's r-slots)
//     -> removes 32 v_add + 32 zero-movs per step.
// Everything else identical to round 6.
// ---------------------------------------------------------------------------

typedef _Float16 h8 __attribute__((ext_vector_type(8)));
typedef _Float16 hv4 __attribute__((ext_vector_type(4)));
typedef float f4 __attribute__((ext_vector_type(4)));

#define NB    4096
#define TSEQ  50
#define DOBS  64
#define DACT  16
#define HD    256
#define DOUT  64
#define NL    5

#define NKT   11        // K-tiles of 32 covering 352 = 80 (x) + 256 (h) + 16 pad
#define AROW  360       // LDS A-row stride in halves
#define MTILE 16
#define NWG   (NB / MTILE)   // 256
#define NTHR  512            // 8 waves

// ws layout in halves (written by repack_kernel)
#define WS_MLP   (704 * 512)
#define WS_WOUT  (WS_MLP + 640 * 512)

// LDS layout (halves): As0 | As1 | Wcache(8 waves x WCB blocks)
#define LDS_AS     (MTILE * AROW)      // 5760 per panel
#define LDS_WCOFF  (2 * LDS_AS)        // 11520
#define WCB        16                  // LDS-resident blocks per wave (cb0 kt6..9)
#define LDS_HALVES (LDS_WCOFF + 8 * WCB * 512)   // 77056
#define LDS_BYTES  (LDS_HALVES * 2)              // 154112  (<= 160 KiB)
static_assert(LDS_BYTES <= 160 * 1024, "LDS overflow");

// streaming: cb1 kt0..10 (44) + cb0 kt10 (4) = 48 blocks/wave/step,
// through an 8-slot ring that persists ACROSS steps (48 % 8 == 0).
#define SB_P     8
#define NSTREAM  48

// Barrier that does NOT drain vmcnt: cross-wave data is ds_write-only (h, x
// panels), covered by lgkmcnt(0). Global loads (stream ring, x prefetch) are
// private-register destinations -> safe to remain in flight across s_barrier.
__device__ __forceinline__ void lds_barrier() {
  asm volatile("s_waitcnt lgkmcnt(0)\n\ts_barrier" ::: "memory");
}

// sigmoid via native v_exp_f32 + v_rcp_f32 (1-ulp; fp16 weights dominate err).
__device__ __forceinline__ float sigf(float x) {
  const float e = __builtin_amdgcn_exp2f(x * -1.44269504088896f);
  return __builtin_amdgcn_rcpf(1.f + e);
}

// stream order c -> block offset (halves) rel. to wave base (w*2*NKT*512):
//   c in [0,44):  cb1, kt = c>>2, g = c&3   -> ((g*16+1)*NKT + kt)*512
//   c in [44,48): cb0 kt10, g = c-44        -> ((g*16+0)*NKT + 10)*512
__device__ constexpr int soff(int c) {
  if (c < 44) { const int g = c & 3, kt = c >> 2; return ((g * 16 + 1) * NKT + kt) * 512; }
  const int g = c - 44; return ((g * 16) * NKT + 10) * 512;
}

// --------------------------- weight repack ---------------------------------
__global__ void __launch_bounds__(256) repack_kernel(
    const float* __restrict__ Wi, const float* __restrict__ Wh,
    const float* __restrict__ mlpW, const float* __restrict__ Wout,
    _Float16* __restrict__ wsW)
{
  const int gt  = blockIdx.x * 256 + threadIdx.x;
  const int gb  = gt >> 6;
  const int l   = gt & 63;
  const int l15 = l & 15;
  const int kb  = (l >> 4) * 8;
  h8 v;
  if (gb < 704) {                       // LSTM: Wcat[k][n], k<80 -> Wi, k<336 -> Wh, else 0
    const int nt = gb / NKT, kt = gb - nt * NKT;
    const int n  = nt * 16 + l15;
#pragma unroll
    for (int j = 0; j < 8; ++j) {
      const int k = kt * 32 + kb + j;
      float s = 0.f;
      if (k < 80)       s = Wi[k * 1024 + n];
      else if (k < 336) s = Wh[(k - 80) * 1024 + n];
      v[j] = (_Float16)s;
    }
  } else if (gb < 1344) {               // MLP layer weights [5][256][256]
    const int b2 = gb - 704;
    const int L  = b2 >> 7, rr = b2 & 127;
    const int nt = rr >> 3, kt = rr & 7;
    const int n  = nt * 16 + l15;
#pragma unroll
    for (int j = 0; j < 8; ++j) {
      const int k = kt * 32 + kb + j;
      v[j] = (_Float16)mlpW[(size_t)L * 65536 + k * 256 + n];
    }
  } else {                              // Wout [256][64]
    const int b3 = gb - 1344;
    const int nt = b3 >> 3, kt = b3 & 7;
    const int n  = nt * 16 + l15;
#pragma unroll
    for (int j = 0; j < 8; ++j) {
      const int k = kt * 32 + kb + j;
      v[j] = (_Float16)Wout[k * 64 + n];
    }
  }
  *(h8*)&wsW[(size_t)gb * 512 + l * 8] = v;
}

// ------------------------------ main kernel --------------------------------
__global__ void __launch_bounds__(NTHR, 2) lstm_kernel(
    const float* __restrict__ traj, const float* __restrict__ acts,
    const float* __restrict__ bh,   const float* __restrict__ mlpb,
    const float* __restrict__ bout, const _Float16* __restrict__ wsW,
    float* __restrict__ out)
{
  extern __shared__ __align__(16) _Float16 lds[];
  _Float16* As0 = lds;
  _Float16* As1 = lds + LDS_AS;
  _Float16* Wc  = lds + LDS_WCOFF;

  const int tid = threadIdx.x;
  const int w   = tid >> 6;        // wave 0..7: owns h-cols [32w, 32w+32)
  const int l   = tid & 63;
  const int l15 = l & 15;
  const int lq  = l >> 4;
  const int rbase = blockIdx.x * MTILE;

  // Zero both A panels (h starts 0; pad cols 336..359 stay 0 forever).
  for (int i = tid; i < 2 * LDS_AS; i += NTHR) lds[i] = (_Float16)0.f;

  // LDS-resident: 16 blocks/wave = (cb0, kt6..9, g0..3)
#pragma unroll
  for (int j = 0; j < WCB; ++j) {
    const int g = j & 3, kt = 6 + (j >> 2);
    const h8 v = *(const h8*)&wsW[(size_t)((g * 16 + w * 2) * NKT + kt) * 512 + l * 8];
    *(h8*)&Wc[(w * WCB + j) * 512 + l * 8] = v;
  }

  // Register-resident: 24 blocks/wave = (cb0, kt0..5, g0..3) — AGPR-backed.
  h8 rw[24];
#pragma unroll
  for (int kt = 0; kt < 6; ++kt)
#pragma unroll
    for (int g = 0; g < 4; ++g)
      rw[kt * 4 + g] = *(const h8*)&wsW[(size_t)((g * 16 + w * 2) * NKT + kt) * 512 + l * 8];

  // Persistent cell state + biases
  float c[2][4];
#pragma unroll
  for (int cb = 0; cb < 2; ++cb)
#pragma unroll
    for (int r = 0; r < 4; ++r) c[cb][r] = 0.f;

  float bias[4][2];
#pragma unroll
  for (int g = 0; g < 4; ++g) {
    bias[g][0] = bh[g * 256 + w * 32 + l15];
    bias[g][1] = bh[g * 256 + w * 32 + 16 + l15];
  }

  lds_barrier();

  // Stage x_0 into As0 cols 0..79 (traj via waves 0-3, acts via waves 4-7)
  if (tid < 256) {
    const int r = tid >> 4, q = tid & 15;
    const float4 v = *(const float4*)&traj[(size_t)(rbase + r) * (TSEQ * DOBS) + q * 4];
    hv4 hx = { (_Float16)v.x, (_Float16)v.y, (_Float16)v.z, (_Float16)v.w };
    *(hv4*)&As0[r * AROW + q * 4] = hx;
  } else {
    const int r = (tid - 256) >> 4, q = (tid - 256) & 15;
    As0[r * AROW + 64 + q] = (_Float16)acts[(size_t)(rbase + r) * (TSEQ * DACT) + q];
  }
  lds_barrier();

  unsigned long long wbits = (unsigned long long)(const void*)wsW;

  // Persistent 8-slot stream ring. Primed once here; thereafter each step's
  // last 8 refills prime the next step (stream order periodic mod 48).
  h8 sb[SB_P];
  {
    const _Float16* wlb0 = wsW + (size_t)(w * 2 * NKT) * 512 + l * 8;
#pragma unroll
    for (int cc = 0; cc < SB_P; ++cc) sb[cc] = *(const h8*)&wlb0[soff(cc)];
  }

  auto step = [&](int t, const _Float16* buf, _Float16* nbuf) {
    // Memory clobber: stream loads can't be hoisted/CSE'd across steps and
    // rw[] can't be legally rematerialized from wsW.
    asm volatile("" : "+s"(wbits) : : "memory");
    const _Float16* wst = (const _Float16*)wbits;
    const _Float16* wlb = wst + (size_t)(w * 2 * NKT) * 512 + l * 8;

    // x(t+1): load to registers now, store to LDS at end of step.
    float4 xv; float xa;
    const bool havex = (t + 1 < TSEQ);
    if (havex) {
      if (tid < 256) {
        const int r = tid >> 4, q = tid & 15;
        xv = *(const float4*)&traj[(size_t)(rbase + r) * (TSEQ * DOBS) + (t + 1) * DOBS + q * 4];
      } else {
        const int r = (tid - 256) >> 4, q = (tid - 256) & 15;
        xa = acts[(size_t)(rbase + r) * (TSEQ * DACT) + (t + 1) * DACT + q];
      }
    }

    // ---------------- fused K-loop: cb0 (on-chip) + cb1 (streamed) ---------
    // Bias folded into the C initializer: a lane's 4 r-slots share one output
    // column, so the bias is uniform across the accumulator registers.
    f4 acc0[4], acc1[4];
#pragma unroll
    for (int g = 0; g < 4; ++g) {
      const float b0 = bias[g][0], b1 = bias[g][1];
      acc0[g] = f4{b0, b0, b0, b0};
      acc1[g] = f4{b1, b1, b1, b1};
    }

#pragma unroll
    for (int kt = 0; kt < NKT; ++kt) {
      const h8 a0 = *(const h8*)&buf[l15 * AROW + kt * 32 + lq * 8];
#pragma unroll
      for (int g = 0; g < 4; ++g) {
        // cb0 fragment: registers (kt<6), LDS cache (kt6..9), stream (kt10,
        // ring slots 4..7 = positions 44..47, refilled at kt9).
        h8 bf0;
        if (kt < 6)       bf0 = rw[kt * 4 + g];
        else if (kt < 10) bf0 = *(const h8*)&Wc[(w * WCB + (kt - 6) * 4 + g) * 512 + l * 8];
        else              bf0 = sb[4 + g];
        acc0[g] = __builtin_amdgcn_mfma_f32_16x16x32_f16(a0, bf0, acc0[g], 0, 0, 0);

        // cb1 fragment: stream position cc; refill slot with position cc+8
        // (mod 48 -> the last 8 refills fetch NEXT step's first blocks).
        const int cc = kt * 4 + g;
        acc1[g] = __builtin_amdgcn_mfma_f32_16x16x32_f16(a0, sb[cc % SB_P], acc1[g], 0, 0, 0);
        sb[cc % SB_P] = *(const h8*)&wlb[soff((cc + SB_P) % NSTREAM)];
        if (kt == 10) {   // also re-prime the cb0-kt10 slots for next step
          sb[4 + g] = *(const h8*)&wlb[soff(4 + g)];
        }
      }
    }

    // ---------------- cell update for both column halves -------------------
    {
      const int colh = 80 + w * 32 + l15;   // cb=0
#pragma unroll
      for (int r = 0; r < 4; ++r) {
        const float zi = acc0[0][r];
        const float zf = acc0[1][r];
        const float zg = acc0[2][r];
        const float zo = acc0[3][r];
        const float ig = sigf(zi), fg = sigf(zf), og = sigf(zo);
        const float gg = zg * sigf(zg);
        const float cn = fg * c[0][r] + ig * gg;
        c[0][r] = cn;
        nbuf[(lq * 4 + r) * AROW + colh] = (_Float16)(og * cn * sigf(cn));
      }
    }
    {
      const int colh = 80 + w * 32 + 16 + l15;   // cb=1
#pragma unroll
      for (int r = 0; r < 4; ++r) {
        const float zi = acc1[0][r];
        const float zf = acc1[1][r];
        const float zg = acc1[2][r];
        const float zo = acc1[3][r];
        const float ig = sigf(zi), fg = sigf(zf), og = sigf(zo);
        const float gg = zg * sigf(zg);
        const float cn = fg * c[1][r] + ig * gg;
        c[1][r] = cn;
        nbuf[(lq * 4 + r) * AROW + colh] = (_Float16)(og * cn * sigf(cn));
      }
    }

    // Deferred x(t+1) store into nbuf cols 0..79.
    if (havex) {
      if (tid < 256) {
        const int r = tid >> 4, q = tid & 15;
        hv4 hx = { (_Float16)xv.x, (_Float16)xv.y, (_Float16)xv.z, (_Float16)xv.w };
        *(hv4*)&nbuf[r * AROW + q * 4] = hx;
      } else {
        const int r = (tid - 256) >> 4, q = (tid - 256) & 15;
        nbuf[r * AROW + 64 + q] = (_Float16)xa;
      }
    }
  };

#pragma unroll 1
  for (int t = 0; t < TSEQ; t += 2) {
    step(t, As0, As1);
    lds_barrier();           // LDS-only: stream ring stays in flight
    step(t + 1, As1, As0);
    lds_barrier();
  }

  // ---------------- MLP head ----------------
  // Final h in As0 cols 80..335. Move to As1 cols 0..255.
  for (int i = tid; i < MTILE * HD; i += NTHR) {
    const int r = i >> 8, cc = i & 255;
    As1[r * AROW + cc] = As0[r * AROW + 80 + cc];
  }
  lds_barrier();

#pragma unroll 1
  for (int L = 0; L < NL; ++L) {
    const _Float16* in = (L & 1) ? As0 : As1;
    _Float16*       ob = (L & 1) ? As1 : As0;
    const _Float16* wl = wsW + WS_MLP + (size_t)L * (128 * 512);
    float bcol[2];
    bcol[0] = mlpb[L * HD + w * 32 + l15];
    bcol[1] = mlpb[L * HD + w * 32 + 16 + l15];

    f4 acc[2];
    acc[0] = f4{bcol[0], bcol[0], bcol[0], bcol[0]};
    acc[1] = f4{bcol[1], bcol[1], bcol[1], bcol[1]};
#pragma unroll
    for (int kt = 0; kt < 8; ++kt) {
      const h8 a0 = *(const h8*)&in[l15 * AROW + kt * 32 + lq * 8];
#pragma unroll
      for (int cb = 0; cb < 2; ++cb) {
        const h8 bf = *(const h8*)&wl[(size_t)((w * 2 + cb) * 8 + kt) * 512 + l * 8];
        acc[cb] = __builtin_amdgcn_mfma_f32_16x16x32_f16(a0, bf, acc[cb], 0, 0, 0);
      }
    }
#pragma unroll
    for (int cb = 0; cb < 2; ++cb)
#pragma unroll
      for (int r = 0; r < 4; ++r) {
        const float z = acc[cb][r];
        ob[(lq * 4 + r) * AROW + w * 32 + cb * 16 + l15] = (_Float16)(z * sigf(z));
      }
    lds_barrier();
  }

  // Output layer: final activations in As0 (NL=5 odd). N=64 -> waves 0..3.
  if (w < 4) {
    const _Float16* wo = wsW + WS_WOUT;
    const float bo = bout[w * 16 + l15];
    f4 acc0 = f4{bo, bo, bo, bo};
#pragma unroll
    for (int kt = 0; kt < 8; ++kt) {
      const h8 a0 = *(const h8*)&As0[l15 * AROW + kt * 32 + lq * 8];
      const h8 bf = *(const h8*)&wo[(size_t)(w * 8 + kt) * 512 + l * 8];
      acc0 = __builtin_amdgcn_mfma_f32_16x16x32_f16(a0, bf, acc0, 0, 0, 0);
    }
#pragma unroll
    for (int r = 0; r < 4; ++r)
      out[(size_t)(rbase + lq * 4 + r) * DOUT + w * 16 + l15] = acc0[r];
  }
}

// ------------------------------- launcher ----------------------------------
extern "C" void kernel_launch(void* const* d_in, const int* in_sizes, int n_in,
                              void* d_out, int out_size, void* d_ws, size_t ws_size,
                              hipStream_t stream)
{
  const float* traj = (const float*)d_in[0];
  const float* acts = (const float*)d_in[1];
  const float* Wi   = (const float*)d_in[2];
  const float* Wh   = (const float*)d_in[3];
  const float* bh   = (const float*)d_in[4];
  const float* mlpW = (const float*)d_in[5];
  const float* mlpb = (const float*)d_in[6];
  const float* Wout = (const float*)d_in[7];
  const float* bout = (const float*)d_in[8];
  _Float16* wsW = (_Float16*)d_ws;   // needs 1,409,024 bytes of workspace

  (void)hipFuncSetAttribute((const void*)lstm_kernel,
                            hipFuncAttributeMaxDynamicSharedMemorySize, LDS_BYTES);

  repack_kernel<<<344, 256, 0, stream>>>(Wi, Wh, mlpW, Wout, wsW);
  lstm_kernel<<<NWG, NTHR, LDS_BYTES, stream>>>(traj, acts, bh, mlpb, bout, wsW, (float*)d_out);
}

// Round 8
// 320.921 us; speedup vs baseline: 1.1050x; 1.1050x over previous
//
#include <hip/hip_runtime.h>
#include <hip/hip_fp16.h>

// ---------------------------------------------------------------------------
// DeterministicLSTMSensorBasedForwardDynamics on MI355X (gfx950) — round 8
//
// Round-7 post-mortem: lds_barrier + bias-fold together pushed arch VGPRs
// past 128 (AGPR side is structurally full: rw 96 + acc 32) -> hot-loop
// spill (WRITE 1->12 MB) -> 298 us. Experiment confounded. Round 8 is the
// DE-CONFOUNDED version: exact round-6 code (best known, 263 us, VGPR 124,
// no spill) with ONE change:
//   * the 50 t-loop barriers use an LDS-only barrier
//     (s_waitcnt lgkmcnt(0); s_barrier) so the cross-step stream ring's
//     global loads stay in flight across the barrier. MLP/staging barriers
//     keep __syncthreads (full drain there is harmless and gives the
//     allocator a clean region boundary).
//   * bias-fold REVERTED (r6 gate code).
// Decision rule: WRITE clean + dur ~unchanged -> structural bound -> ROOFLINE.
// ---------------------------------------------------------------------------

typedef _Float16 h8 __attribute__((ext_vector_type(8)));
typedef _Float16 hv4 __attribute__((ext_vector_type(4)));
typedef float f4 __attribute__((ext_vector_type(4)));

#define NB    4096
#define TSEQ  50
#define DOBS  64
#define DACT  16
#define HD    256
#define DOUT  64
#define NL    5

#define NKT   11        // K-tiles of 32 covering 352 = 80 (x) + 256 (h) + 16 pad
#define AROW  360       // LDS A-row stride in halves
#define MTILE 16
#define NWG   (NB / MTILE)   // 256
#define NTHR  512            // 8 waves

// ws layout in halves (written by repack_kernel)
#define WS_MLP   (704 * 512)
#define WS_WOUT  (WS_MLP + 640 * 512)

// LDS layout (halves): As0 | As1 | Wcache(8 waves x WCB blocks)
#define LDS_AS     (MTILE * AROW)      // 5760 per panel
#define LDS_WCOFF  (2 * LDS_AS)        // 11520
#define WCB        16                  // LDS-resident blocks per wave (cb0 kt6..9)
#define LDS_HALVES (LDS_WCOFF + 8 * WCB * 512)   // 77056
#define LDS_BYTES  (LDS_HALVES * 2)              // 154112  (<= 160 KiB)
static_assert(LDS_BYTES <= 160 * 1024, "LDS overflow");

// streaming: cb1 kt0..10 (44) + cb0 kt10 (4) = 48 blocks/wave/step,
// through an 8-slot ring that persists ACROSS steps (48 % 8 == 0).
#define SB_P     8
#define NSTREAM  48

// Barrier that does NOT drain vmcnt: cross-wave data dependencies at the
// t-loop barrier are ds_write-only (h and x panels), covered by lgkmcnt(0).
// In-flight global loads (stream ring, x prefetch) target private VGPRs and
// are synchronized by their own vmcnt-before-use waits -> legal to keep
// flying across s_barrier.
__device__ __forceinline__ void lds_barrier() {
  asm volatile("s_waitcnt lgkmcnt(0)\n\ts_barrier" ::: "memory");
}

// sigmoid via native v_exp_f32 + v_rcp_f32 (1-ulp; fp16 weights dominate err).
__device__ __forceinline__ float sigf(float x) {
  const float e = __builtin_amdgcn_exp2f(x * -1.44269504088896f);
  return __builtin_amdgcn_rcpf(1.f + e);
}

// stream order c -> block offset (halves) rel. to wave base (w*2*NKT*512):
//   c in [0,44):  cb1, kt = c>>2, g = c&3   -> ((g*16+1)*NKT + kt)*512
//   c in [44,48): cb0 kt10, g = c-44        -> ((g*16+0)*NKT + 10)*512
__device__ constexpr int soff(int c) {
  if (c < 44) { const int g = c & 3, kt = c >> 2; return ((g * 16 + 1) * NKT + kt) * 512; }
  const int g = c - 44; return ((g * 16) * NKT + 10) * 512;
}

// --------------------------- weight repack ---------------------------------
__global__ void __launch_bounds__(256) repack_kernel(
    const float* __restrict__ Wi, const float* __restrict__ Wh,
    const float* __restrict__ mlpW, const float* __restrict__ Wout,
    _Float16* __restrict__ wsW)
{
  const int gt  = blockIdx.x * 256 + threadIdx.x;
  const int gb  = gt >> 6;
  const int l   = gt & 63;
  const int l15 = l & 15;
  const int kb  = (l >> 4) * 8;
  h8 v;
  if (gb < 704) {                       // LSTM: Wcat[k][n], k<80 -> Wi, k<336 -> Wh, else 0
    const int nt = gb / NKT, kt = gb - nt * NKT;
    const int n  = nt * 16 + l15;
#pragma unroll
    for (int j = 0; j < 8; ++j) {
      const int k = kt * 32 + kb + j;
      float s = 0.f;
      if (k < 80)       s = Wi[k * 1024 + n];
      else if (k < 336) s = Wh[(k - 80) * 1024 + n];
      v[j] = (_Float16)s;
    }
  } else if (gb < 1344) {               // MLP layer weights [5][256][256]
    const int b2 = gb - 704;
    const int L  = b2 >> 7, rr = b2 & 127;
    const int nt = rr >> 3, kt = rr & 7;
    const int n  = nt * 16 + l15;
#pragma unroll
    for (int j = 0; j < 8; ++j) {
      const int k = kt * 32 + kb + j;
      v[j] = (_Float16)mlpW[(size_t)L * 65536 + k * 256 + n];
    }
  } else {                              // Wout [256][64]
    const int b3 = gb - 1344;
    const int nt = b3 >> 3, kt = b3 & 7;
    const int n  = nt * 16 + l15;
#pragma unroll
    for (int j = 0; j < 8; ++j) {
      const int k = kt * 32 + kb + j;
      v[j] = (_Float16)Wout[k * 64 + n];
    }
  }
  *(h8*)&wsW[(size_t)gb * 512 + l * 8] = v;
}

// ------------------------------ main kernel --------------------------------
__global__ void __launch_bounds__(NTHR, 2) lstm_kernel(
    const float* __restrict__ traj, const float* __restrict__ acts,
    const float* __restrict__ bh,   const float* __restrict__ mlpb,
    const float* __restrict__ bout, const _Float16* __restrict__ wsW,
    float* __restrict__ out)
{
  extern __shared__ __align__(16) _Float16 lds[];
  _Float16* As0 = lds;
  _Float16* As1 = lds + LDS_AS;
  _Float16* Wc  = lds + LDS_WCOFF;

  const int tid = threadIdx.x;
  const int w   = tid >> 6;        // wave 0..7: owns h-cols [32w, 32w+32)
  const int l   = tid & 63;
  const int l15 = l & 15;
  const int lq  = l >> 4;
  const int rbase = blockIdx.x * MTILE;

  // Zero both A panels (h starts 0; pad cols 336..359 stay 0 forever).
  for (int i = tid; i < 2 * LDS_AS; i += NTHR) lds[i] = (_Float16)0.f;

  // LDS-resident: 16 blocks/wave = (cb0, kt6..9, g0..3)
#pragma unroll
  for (int j = 0; j < WCB; ++j) {
    const int g = j & 3, kt = 6 + (j >> 2);
    const h8 v = *(const h8*)&wsW[(size_t)((g * 16 + w * 2) * NKT + kt) * 512 + l * 8];
    *(h8*)&Wc[(w * WCB + j) * 512 + l * 8] = v;
  }

  // Register-resident: 24 blocks/wave = (cb0, kt0..5, g0..3) — AGPR-backed.
  h8 rw[24];
#pragma unroll
  for (int kt = 0; kt < 6; ++kt)
#pragma unroll
    for (int g = 0; g < 4; ++g)
      rw[kt * 4 + g] = *(const h8*)&wsW[(size_t)((g * 16 + w * 2) * NKT + kt) * 512 + l * 8];

  // Persistent cell state + biases
  float c[2][4];
#pragma unroll
  for (int cb = 0; cb < 2; ++cb)
#pragma unroll
    for (int r = 0; r < 4; ++r) c[cb][r] = 0.f;

  float bias[4][2];
#pragma unroll
  for (int g = 0; g < 4; ++g) {
    bias[g][0] = bh[g * 256 + w * 32 + l15];
    bias[g][1] = bh[g * 256 + w * 32 + 16 + l15];
  }

  __syncthreads();

  // Stage x_0 into As0 cols 0..79 (traj via waves 0-3, acts via waves 4-7)
  if (tid < 256) {
    const int r = tid >> 4, q = tid & 15;
    const float4 v = *(const float4*)&traj[(size_t)(rbase + r) * (TSEQ * DOBS) + q * 4];
    hv4 hx = { (_Float16)v.x, (_Float16)v.y, (_Float16)v.z, (_Float16)v.w };
    *(hv4*)&As0[r * AROW + q * 4] = hx;
  } else {
    const int r = (tid - 256) >> 4, q = (tid - 256) & 15;
    As0[r * AROW + 64 + q] = (_Float16)acts[(size_t)(rbase + r) * (TSEQ * DACT) + q];
  }
  __syncthreads();

  unsigned long long wbits = (unsigned long long)(const void*)wsW;

  // Persistent 8-slot stream ring. Primed once here; thereafter each step's
  // last 8 refills prime the next step (stream order periodic mod 48).
  h8 sb[SB_P];
  {
    const _Float16* wlb0 = wsW + (size_t)(w * 2 * NKT) * 512 + l * 8;
#pragma unroll
    for (int cc = 0; cc < SB_P; ++cc) sb[cc] = *(const h8*)&wlb0[soff(cc)];
  }

  auto step = [&](int t, const _Float16* buf, _Float16* nbuf) {
    // Memory clobber: stream loads can't be hoisted/CSE'd across steps and
    // rw[] can't be legally rematerialized from wsW.
    asm volatile("" : "+s"(wbits) : : "memory");
    const _Float16* wst = (const _Float16*)wbits;
    const _Float16* wlb = wst + (size_t)(w * 2 * NKT) * 512 + l * 8;

    // x(t+1): load to registers now, store to LDS at end of step.
    float4 xv; float xa;
    const bool havex = (t + 1 < TSEQ);
    if (havex) {
      if (tid < 256) {
        const int r = tid >> 4, q = tid & 15;
        xv = *(const float4*)&traj[(size_t)(rbase + r) * (TSEQ * DOBS) + (t + 1) * DOBS + q * 4];
      } else {
        const int r = (tid - 256) >> 4, q = (tid - 256) & 15;
        xa = acts[(size_t)(rbase + r) * (TSEQ * DACT) + (t + 1) * DACT + q];
      }
    }

    // ---------------- fused K-loop: cb0 (on-chip) + cb1 (streamed) ---------
    f4 acc0[4], acc1[4];
#pragma unroll
    for (int g = 0; g < 4; ++g) {
      acc0[g] = f4{0.f, 0.f, 0.f, 0.f};
      acc1[g] = f4{0.f, 0.f, 0.f, 0.f};
    }

#pragma unroll
    for (int kt = 0; kt < NKT; ++kt) {
      const h8 a0 = *(const h8*)&buf[l15 * AROW + kt * 32 + lq * 8];
#pragma unroll
      for (int g = 0; g < 4; ++g) {
        // cb0 fragment: registers (kt<6), LDS cache (kt6..9), stream (kt10,
        // ring slots 4..7 = positions 44..47, refilled at kt9).
        h8 bf0;
        if (kt < 6)       bf0 = rw[kt * 4 + g];
        else if (kt < 10) bf0 = *(const h8*)&Wc[(w * WCB + (kt - 6) * 4 + g) * 512 + l * 8];
        else              bf0 = sb[4 + g];
        acc0[g] = __builtin_amdgcn_mfma_f32_16x16x32_f16(a0, bf0, acc0[g], 0, 0, 0);

        // cb1 fragment: stream position cc; refill slot with position cc+8
        // (mod 48 -> the last 8 refills fetch NEXT step's first blocks).
        const int cc = kt * 4 + g;
        acc1[g] = __builtin_amdgcn_mfma_f32_16x16x32_f16(a0, sb[cc % SB_P], acc1[g], 0, 0, 0);
        sb[cc % SB_P] = *(const h8*)&wlb[soff((cc + SB_P) % NSTREAM)];
        if (kt == 10) {   // also re-prime the cb0-kt10 slots for next step
          sb[4 + g] = *(const h8*)&wlb[soff(4 + g)];
        }
      }
    }

    // ---------------- cell update for both column halves -------------------
    {
      const int colh = 80 + w * 32 + l15;   // cb=0
#pragma unroll
      for (int r = 0; r < 4; ++r) {
        const float zi = acc0[0][r] + bias[0][0];
        const float zf = acc0[1][r] + bias[1][0];
        const float zg = acc0[2][r] + bias[2][0];
        const float zo = acc0[3][r] + bias[3][0];
        const float ig = sigf(zi), fg = sigf(zf), og = sigf(zo);
        const float gg = zg * sigf(zg);
        const float cn = fg * c[0][r] + ig * gg;
        c[0][r] = cn;
        nbuf[(lq * 4 + r) * AROW + colh] = (_Float16)(og * cn * sigf(cn));
      }
    }
    {
      const int colh = 80 + w * 32 + 16 + l15;   // cb=1
#pragma unroll
      for (int r = 0; r < 4; ++r) {
        const float zi = acc1[0][r] + bias[0][1];
        const float zf = acc1[1][r] + bias[1][1];
        const float zg = acc1[2][r] + bias[2][1];
        const float zo = acc1[3][r] + bias[3][1];
        const float ig = sigf(zi), fg = sigf(zf), og = sigf(zo);
        const float gg = zg * sigf(zg);
        const float cn = fg * c[1][r] + ig * gg;
        c[1][r] = cn;
        nbuf[(lq * 4 + r) * AROW + colh] = (_Float16)(og * cn * sigf(cn));
      }
    }

    // Deferred x(t+1) store into nbuf cols 0..79.
    if (havex) {
      if (tid < 256) {
        const int r = tid >> 4, q = tid & 15;
        hv4 hx = { (_Float16)xv.x, (_Float16)xv.y, (_Float16)xv.z, (_Float16)xv.w };
        *(hv4*)&nbuf[r * AROW + q * 4] = hx;
      } else {
        const int r = (tid - 256) >> 4, q = (tid - 256) & 15;
        nbuf[r * AROW + 64 + q] = (_Float16)xa;
      }
    }
  };

#pragma unroll 1
  for (int t = 0; t < TSEQ; t += 2) {
    step(t, As0, As1);
    lds_barrier();           // LDS-only: stream ring stays in flight
    step(t + 1, As1, As0);
    lds_barrier();
  }

  // ---------------- MLP head ----------------
  // Final h in As0 cols 80..335. Move to As1 cols 0..255.
  for (int i = tid; i < MTILE * HD; i += NTHR) {
    const int r = i >> 8, cc = i & 255;
    As1[r * AROW + cc] = As0[r * AROW + 80 + cc];
  }
  __syncthreads();

#pragma unroll 1
  for (int L = 0; L < NL; ++L) {
    const _Float16* in = (L & 1) ? As0 : As1;
    _Float16*       ob = (L & 1) ? As1 : As0;
    const _Float16* wl = wsW + WS_MLP + (size_t)L * (128 * 512);
    float bcol[2];
    bcol[0] = mlpb[L * HD + w * 32 + l15];
    bcol[1] = mlpb[L * HD + w * 32 + 16 + l15];

    f4 acc[2];
    acc[0] = f4{0.f, 0.f, 0.f, 0.f};
    acc[1] = f4{0.f, 0.f, 0.f, 0.f};
#pragma unroll
    for (int kt = 0; kt < 8; ++kt) {
      const h8 a0 = *(const h8*)&in[l15 * AROW + kt * 32 + lq * 8];
#pragma unroll
      for (int cb = 0; cb < 2; ++cb) {
        const h8 bf = *(const h8*)&wl[(size_t)((w * 2 + cb) * 8 + kt) * 512 + l * 8];
        acc[cb] = __builtin_amdgcn_mfma_f32_16x16x32_f16(a0, bf, acc[cb], 0, 0, 0);
      }
    }
#pragma unroll
    for (int cb = 0; cb < 2; ++cb)
#pragma unroll
      for (int r = 0; r < 4; ++r) {
        const float z = acc[cb][r] + bcol[cb];
        ob[(lq * 4 + r) * AROW + w * 32 + cb * 16 + l15] = (_Float16)(z * sigf(z));
      }
    __syncthreads();
  }

  // Output layer: final activations in As0 (NL=5 odd). N=64 -> waves 0..3.
  if (w < 4) {
    const _Float16* wo = wsW + WS_WOUT;
    const float bo = bout[w * 16 + l15];
    f4 acc0 = f4{0.f, 0.f, 0.f, 0.f};
#pragma unroll
    for (int kt = 0; kt < 8; ++kt) {
      const h8 a0 = *(const h8*)&As0[l15 * AROW + kt * 32 + lq * 8];
      const h8 bf = *(const h8*)&wo[(size_t)(w * 8 + kt) * 512 + l * 8];
      acc0 = __builtin_amdgcn_mfma_f32_16x16x32_f16(a0, bf, acc0, 0, 0, 0);
    }
#pragma unroll
    for (int r = 0; r < 4; ++r)
      out[(size_t)(rbase + lq * 4 + r) * DOUT + w * 16 + l15] = acc0[r] + bo;
  }
}

// ------------------------------- launcher ----------------------------------
extern "C" void kernel_launch(void* const* d_in, const int* in_sizes, int n_in,
                              void* d_out, int out_size, void* d_ws, size_t ws_size,
                              hipStream_t stream)
{
  const float* traj = (const float*)d_in[0];
  const float* acts = (const float*)d_in[1];
  const float* Wi   = (const float*)d_in[2];
  const float* Wh   = (const float*)d_in[3];
  const float* bh   = (const float*)d_in[4];
  const float* mlpW = (const float*)d_in[5];
  const float* mlpb = (const float*)d_in[6];
  const float* Wout = (const float*)d_in[7];
  const float* bout = (const float*)d_in[8];
  _Float16* wsW = (_Float16*)d_ws;   // needs 1,409,024 bytes of workspace

  (void)hipFuncSetAttribute((const void*)lstm_kernel,
                            hipFuncAttributeMaxDynamicSharedMemorySize, LDS_BYTES);

  repack_kernel<<<344, 256, 0, stream>>>(Wi, Wh, mlpW, Wout, wsW);
  lstm_kernel<<<NWG, NTHR, LDS_BYTES, stream>>>(traj, acts, bh, mlpb, bout, wsW, (float*)d_out);
}